// Round 1
// baseline (352.478 us; speedup 1.0000x reference)
//
#include <hip/hip_runtime.h>
#include <math.h>

#define NB 32
#define NP 8732
#define NC 81
#define NM 20

// ---------------- init: zero accumulators ----------------
__global__ __launch_bounds__(64) void init_kernel(unsigned* acc) {
    if (threadIdx.x < 4) acc[threadIdx.x] = 0u;
}

// ---------------- matching: one block per image ----------------
// acc layout: acc[0]=loc_sum(f32), acc[1]=conf_pos(f32), acc[2]=conf_neg(f32), ((int*)acc)[3]=n_pos_total
__global__ __launch_bounds__(1024)
void match_kernel(const float* __restrict__ plocs,
                  const float* __restrict__ boxes,
                  const int*   __restrict__ labels,
                  const float* __restrict__ priors,
                  float* __restrict__ acc,
                  int*   __restrict__ nposarr,
                  int*   __restrict__ tclass)
{
    const int b = blockIdx.x;
    const int tid = threadIdx.x;
    const int T = 1024;
    const int NW = T / 64;

    __shared__ float ovL[NP];
    __shared__ unsigned char objL[NP];
    __shared__ float bxs[NM][4];
    __shared__ float areaA[NM];
    __shared__ int   labL[NM];
    __shared__ float redv[NW][NM];
    __shared__ int   redp[NW][NM];
    __shared__ int   bestPrior[NM];
    __shared__ float fredS[NW];
    __shared__ int   iredS[NW];

    if (tid < NM * 4) ((float*)bxs)[tid] = boxes[b * NM * 4 + tid];
    if (tid >= 64 && tid < 64 + NM) labL[tid - 64] = labels[b * NM + (tid - 64)];
    __syncthreads();
    if (tid < NM) areaA[tid] = (bxs[tid][2] - bxs[tid][0]) * (bxs[tid][3] - bxs[tid][1]);
    __syncthreads();

    // Phase A: per-prior best object (first-max), per-thread per-object best prior
    float bestv[NM];
    int   bestp[NM];
#pragma unroll
    for (int m = 0; m < NM; m++) { bestv[m] = -1.f; bestp[m] = 0; }

    for (int p = tid; p < NP; p += T) {
        float4 pc = reinterpret_cast<const float4*>(priors)[p];
        float px1 = pc.x - pc.z * 0.5f;
        float py1 = pc.y - pc.w * 0.5f;
        float px2 = pc.x + pc.z * 0.5f;
        float py2 = pc.y + pc.w * 0.5f;
        float pa  = (px2 - px1) * (py2 - py1);
        float bov = -1.f; int bm = 0;
#pragma unroll
        for (int m = 0; m < NM; m++) {
            float ix1 = fmaxf(bxs[m][0], px1);
            float iy1 = fmaxf(bxs[m][1], py1);
            float ix2 = fminf(bxs[m][2], px2);
            float iy2 = fminf(bxs[m][3], py2);
            float iw = fmaxf(ix2 - ix1, 0.f);
            float ih = fmaxf(iy2 - iy1, 0.f);
            float inter = iw * ih;
            float iou = inter / (areaA[m] + pa - inter);
            if (iou > bov)      { bov = iou; bm = m; }          // first max over m
            if (iou > bestv[m]) { bestv[m] = iou; bestp[m] = p; } // first max over p (ascending)
        }
        ovL[p] = bov;
        objL[p] = (unsigned char)bm;
    }

    // Phase B: block-wide per-object argmax over priors (min-index tie-break)
    const int lane = tid & 63, wid = tid >> 6;
#pragma unroll
    for (int m = 0; m < NM; m++) {
        float v = bestv[m]; int pp = bestp[m];
        for (int off = 32; off; off >>= 1) {
            float vo = __shfl_down(v, off);
            int   po = __shfl_down(pp, off);
            if (vo > v || (vo == v && po < pp)) { v = vo; pp = po; }
        }
        if (lane == 0) { redv[wid][m] = v; redp[wid][m] = pp; }
    }
    __syncthreads();
    if (tid < NM) {
        float v = redv[0][tid]; int pp = redp[0][tid];
        for (int w = 1; w < NW; w++) {
            float vo = redv[w][tid]; int po = redp[w][tid];
            if (vo > v || (vo == v && po < pp)) { v = vo; pp = po; }
        }
        bestPrior[tid] = pp;
    }
    __syncthreads();
    // Phase C: force-assign, serial -> last write wins (numpy duplicate-index semantics)
    if (tid == 0) {
        for (int m = 0; m < NM; m++) {
            int pp = bestPrior[m];
            ovL[pp] = 1.0f;
            objL[pp] = (unsigned char)m;
        }
    }
    __syncthreads();

    // Phase D: labels, n_pos, smooth-L1 over positives
    float locsum = 0.f;
    int np = 0;
    for (int p = tid; p < NP; p += T) {
        float ov = ovL[p];
        int m = objL[p];
        int lab = (ov < 0.5f) ? 0 : labL[m];
        tclass[(size_t)b * NP + p] = lab;
        if (lab > 0) {
            np++;
            float4 pc = reinterpret_cast<const float4*>(priors)[p];
            float x1 = bxs[m][0], y1 = bxs[m][1], x2 = bxs[m][2], y2 = bxs[m][3];
            float bcx = (x1 + x2) * 0.5f, bcy = (y1 + y2) * 0.5f;
            float bw = x2 - x1, bh = y2 - y1;
            float g0 = (bcx - pc.x) / (pc.z / 10.f);
            float g1 = (bcy - pc.y) / (pc.w / 10.f);
            float g2 = logf(bw / pc.z) * 5.f;
            float g3 = logf(bh / pc.w) * 5.f;
            float4 pl = reinterpret_cast<const float4*>(plocs)[(size_t)b * NP + p];
            float d, ad;
            d = pl.x - g0; ad = fabsf(d); locsum += (ad < 1.f) ? 0.5f * d * d : ad - 0.5f;
            d = pl.y - g1; ad = fabsf(d); locsum += (ad < 1.f) ? 0.5f * d * d : ad - 0.5f;
            d = pl.z - g2; ad = fabsf(d); locsum += (ad < 1.f) ? 0.5f * d * d : ad - 0.5f;
            d = pl.w - g3; ad = fabsf(d); locsum += (ad < 1.f) ? 0.5f * d * d : ad - 0.5f;
        }
    }
    for (int off = 32; off; off >>= 1) {
        locsum += __shfl_down(locsum, off);
        np     += __shfl_down(np, off);
    }
    if (lane == 0) { fredS[wid] = locsum; iredS[wid] = np; }
    __syncthreads();
    if (tid == 0) {
        float ls = 0.f; int n = 0;
        for (int w = 0; w < NW; w++) { ls += fredS[w]; n += iredS[w]; }
        nposarr[b] = n;
        atomicAdd(&acc[0], ls);
        atomicAdd((int*)acc + 3, n);
    }
}

// ---------------- cross entropy: one wave per row ----------------
__global__ __launch_bounds__(256)
void ce_kernel(const float* __restrict__ scores,
               const int*   __restrict__ tclass,
               float* __restrict__ neg,
               float* __restrict__ acc)
{
    __shared__ float bsum;
    if (threadIdx.x == 0) bsum = 0.f;
    __syncthreads();
    long long w = ((long long)blockIdx.x * blockDim.x + threadIdx.x) >> 6;
    int lane = threadIdx.x & 63;
    if (w < (long long)NB * NP) {
        const float* base = scores + w * NC;
        float v1 = base[lane];
        float v2 = (lane + 64 < NC) ? base[lane + 64] : -INFINITY;
        float mx = fmaxf(v1, v2);
#pragma unroll
        for (int off = 32; off; off >>= 1) mx = fmaxf(mx, __shfl_xor(mx, off));
        float e = expf(v1 - mx) + ((lane + 64 < NC) ? expf(v2 - mx) : 0.f);
#pragma unroll
        for (int off = 32; off; off >>= 1) e += __shfl_xor(e, off);
        int tgt = tclass[w];
        float ce = mx + logf(e) - base[tgt];
        if (lane == 0) {
            if (tgt > 0) { neg[w] = 0.f; atomicAdd(&bsum, ce); }
            else         { neg[w] = ce; }
        }
    }
    __syncthreads();
    if (threadIdx.x == 0 && bsum != 0.f) atomicAdd(&acc[1], bsum);
}

// ---------------- hard-negative mining: one block per image ----------------
__global__ __launch_bounds__(256)
void mine_kernel(const float* __restrict__ neg,
                 const int*   __restrict__ nposarr,
                 float* __restrict__ acc)
{
    __shared__ float vals[NP];
    __shared__ float fredS[4];
    __shared__ int   iredS[4];
    const int b = blockIdx.x;
    const int tid = threadIdx.x;
    const float* src = neg + (size_t)b * NP;
    for (int p = tid; p < NP; p += 256) vals[p] = src[p];
    int k = nposarr[b] * 3;
    if (k > NP) k = NP;
    __syncthreads();
    const int lane = tid & 63, wid = tid >> 6;

    // binary search k-th largest on uint bit pattern (all vals >= 0)
    unsigned lo = 0u, hi = 0x7f7fffffu;
    while (lo < hi) {
        unsigned mid = lo + ((hi - lo + 1u) >> 1);
        float t = __uint_as_float(mid);
        int cnt = 0;
        for (int p = tid; p < NP; p += 256) cnt += (vals[p] >= t) ? 1 : 0;
#pragma unroll
        for (int off = 32; off; off >>= 1) cnt += __shfl_xor(cnt, off);
        if (lane == 0) iredS[wid] = cnt;
        __syncthreads();
        int total = iredS[0] + iredS[1] + iredS[2] + iredS[3];
        __syncthreads();
        if (total >= k) lo = mid; else hi = mid - 1u;
    }
    float t = __uint_as_float(lo);   // k-th largest value
    float s = 0.f; int cg = 0;
    for (int p = tid; p < NP; p += 256) {
        float v = vals[p];
        if (v > t) { s += v; cg++; }
    }
#pragma unroll
    for (int off = 32; off; off >>= 1) { s += __shfl_down(s, off); cg += __shfl_down(cg, off); }
    if (lane == 0) { fredS[wid] = s; iredS[wid] = cg; }
    __syncthreads();
    if (tid == 0) {
        float sum = fredS[0] + fredS[1] + fredS[2] + fredS[3];
        int cG = iredS[0] + iredS[1] + iredS[2] + iredS[3];
        float res = sum + (float)(k - cG) * t;   // exact under ties
        atomicAdd(&acc[2], res);
    }
}

// ---------------- finalize ----------------
__global__ void fin_kernel(const float* __restrict__ acc, float* __restrict__ out)
{
    if (threadIdx.x == 0) {
        float nt = (float)((const int*)acc)[3];
        out[0] = (acc[2] + acc[1]) / nt;       // conf_loss
        out[1] = acc[0] / (nt * 4.f);          // ALPHA * loc_loss, ALPHA = 1
    }
}

extern "C" void kernel_launch(void* const* d_in, const int* in_sizes, int n_in,
                              void* d_out, int out_size, void* d_ws, size_t ws_size,
                              hipStream_t stream)
{
    const float* plocs  = (const float*)d_in[0];
    const float* scores = (const float*)d_in[1];
    const float* boxes  = (const float*)d_in[2];
    const int*   labels = (const int*)d_in[3];
    const float* priors = (const float*)d_in[4];
    float* out = (float*)d_out;

    // ws layout (floats/ints, 4B each):
    // [0..3]  accumulators (loc_sum, conf_pos, conf_neg, n_pos_total)
    // [16..)  nposarr[NB]
    // [64..)  tclass[NB*NP]
    // [64+NB*NP..) neg[NB*NP]
    float* acc    = (float*)d_ws;
    int*   nposarr = (int*)d_ws + 16;
    int*   tclass = (int*)d_ws + 64;
    float* neg    = (float*)d_ws + 64 + NB * NP;

    hipLaunchKernelGGL(init_kernel, dim3(1), dim3(64), 0, stream, (unsigned*)acc);
    hipLaunchKernelGGL(match_kernel, dim3(NB), dim3(1024), 0, stream,
                       plocs, boxes, labels, priors, acc, nposarr, tclass);
    const int rows = NB * NP;                  // 279424, divisible by 4
    hipLaunchKernelGGL(ce_kernel, dim3(rows / 4), dim3(256), 0, stream,
                       scores, tclass, neg, acc);
    hipLaunchKernelGGL(mine_kernel, dim3(NB), dim3(256), 0, stream, neg, nposarr, acc);
    hipLaunchKernelGGL(fin_kernel, dim3(1), dim3(64), 0, stream, acc, out);
}